// Round 13
// baseline (1083.650 us; speedup 1.0000x reference)
//
#include <hip/hip_runtime.h>

#define Q 16
#define SCAN_B 256

__device__ __forceinline__ float wsum(float v){
  #pragma unroll
  for(int o=32;o;o>>=1) v += __shfl_xor(v,o);
  return v;
}
__device__ __forceinline__ float wmaxr(float v){
  #pragma unroll
  for(int o=32;o;o>>=1) v = fmaxf(v,__shfl_xor(v,o));
  return v;
}

// ---- edge kernel (R9-proven form): 16 lanes per pair, one q per lane ----
// Msg stays in EDGE order: reads/writes are two coalesced streams (rows p and
// p+M). Randomness confined to nl (3.2MB, L2-resident). R10/R12 CSR-random
// edge measured 55us; this form back-solves to ~25us in R9.
__global__ void __launch_bounds__(256, 4) k_edge16(
    const int* __restrict__ src, const int* __restrict__ dst,
    const float* msg_in, float* msg_out,
    const float* __restrict__ nl, const float* __restrict__ hc,
    const float* __restrict__ betap,
    float* __restrict__ diffpart, const int* __restrict__ donep, int M)
{
  if (*donep) return;
  const float eb = __expf(*betap) - 1.0f;
  const int q = threadIdx.x & 15;
  const float hq = hc[q];
  const int grp  = (blockIdx.x*blockDim.x + threadIdx.x) >> 4;
  const int ngrp = (gridDim.x*blockDim.x) >> 4;
  float dloc = 0.0f;
  for (int p = grp; p < M; p += ngrp){
    const int u = src[p], v = dst[p];
    const float muv = msg_in[(size_t)p*Q + q];
    const float mvu = msg_in[((size_t)p + (size_t)M)*Q + q];
    const float nlu = nl[(size_t)u*Q + q];
    const float nlv = nl[(size_t)v*Q + q];
    const float lsuv = __logf(fmaf(muv, eb, 1.0f));   // logS of u->v
    const float lsvu = __logf(fmaf(mvu, eb, 1.0f));   // logS of v->u
    float tuv = nlu - lsvu + hq;                      // cavity removes reverse
    float tvu = nlv - lsuv + hq;
    float m1 = tuv, m2 = tvu;
    #pragma unroll
    for (int o=1;o<16;o<<=1){
      m1 = fmaxf(m1, __shfl_xor(m1,o));
      m2 = fmaxf(m2, __shfl_xor(m2,o));
    }
    const float e1 = __expf(tuv-m1), e2 = __expf(tvu-m2);
    float s1 = e1, s2 = e2;
    #pragma unroll
    for (int o=1;o<16;o<<=1){
      s1 += __shfl_xor(s1,o);
      s2 += __shfl_xor(s2,o);
    }
    const float nuv = e1/s1, nvu = e2/s2;
    float d1 = fabsf(nuv-muv), d2 = fabsf(nvu-mvu);
    #pragma unroll
    for (int o=1;o<16;o<<=1){
      d1 += __shfl_xor(d1,o);
      d2 += __shfl_xor(d2,o);
    }
    dloc = fmaxf(dloc, fmaxf(d1,d2));
    msg_out[(size_t)p*Q + q] = nuv;
    msg_out[((size_t)p + (size_t)M)*Q + q] = nvu;
  }
  __shared__ float smx[4];
  float wm = wmaxr(dloc);
  if ((threadIdx.x & 63) == 0) smx[threadIdx.x>>6] = wm;
  __syncthreads();
  if (threadIdx.x == 0)
    diffpart[blockIdx.x] = fmaxf(fmaxf(smx[0],smx[1]), fmaxf(smx[2],smx[3]));
}

// ---- gather (R3-R7-proven form): eid-CSR, one wave per node, 12500 short
// blocks (R9 lesson: never few fat blocks on a dependent chain), NO fences
// (R11 lesson: device fences must be O(100) blocks). mode=1: psi + hpart.
__global__ void __launch_bounds__(256, 4) k_gather(
    const float* __restrict__ msg, const int* __restrict__ offs,
    const int* __restrict__ eid,
    float* __restrict__ nl, const float* __restrict__ hc,
    float* __restrict__ psi, const float* __restrict__ betap,
    const int* __restrict__ donep, float* __restrict__ hpart,
    int N, int mode)
{
  if (mode && *donep) return;
  const int wid = threadIdx.x >> 6;                 // 0..3
  const int n = blockIdx.x*4 + wid;
  const float eb = __expf(*betap) - 1.0f;
  const int lane = threadIdx.x & 63;
  const int sub = lane >> 4, q16 = lane & 15;
  int start = 0, end = 0;
  if (n < N){ start = offs[n]; end = offs[n+1]; }
  float acc = 0.0f;
  int i = start + sub;
  for (; i + 4 < end; i += 8){
    const int e0 = eid[i], e1 = eid[i+4];
    const float x0 = msg[(size_t)e0*Q + q16];
    const float x1 = msg[(size_t)e1*Q + q16];
    acc += __logf(fmaf(x0, eb, 1.0f)) + __logf(fmaf(x1, eb, 1.0f));
  }
  if (i < end)
    acc += __logf(fmaf(msg[(size_t)eid[i]*Q + q16], eb, 1.0f));
  acc += __shfl_xor(acc, 16);
  acc += __shfl_xor(acc, 32);
  if (n < N && sub == 0) nl[(size_t)n*Q + q16] = acc;
  if (!mode) return;
  float t = acc + hc[q16];
  float m = t;
  #pragma unroll
  for (int o=1;o<16;o<<=1) m = fmaxf(m, __shfl_xor(m,o));
  float ex = __expf(t-m);
  float s = ex;
  #pragma unroll
  for (int o=1;o<16;o<<=1) s += __shfl_xor(s,o);
  const float pq = ex/s;
  if (n < N && sub == 0) psi[(size_t)n*Q + q16] = pq;
  __shared__ float smh[4][17];
  if (sub == 0) smh[wid][q16] = (n < N) ? pq : 0.0f;
  __syncthreads();
  if (threadIdx.x < Q)
    hpart[(size_t)blockIdx.x*Q + threadIdx.x] =
      smh[0][threadIdx.x]+smh[1][threadIdx.x]+smh[2][threadIdx.x]+smh[3][threadIdx.x];
}

// ---- merged per-iteration reduce (R7/R10/R12-proven): 49 blocks, 1 fence each ----
__global__ void __launch_bounds__(256) k_hred2(
    const float* __restrict__ hpart, int nrows,
    float* __restrict__ hpart2, int gH,
    const float* __restrict__ diffpart, int nbd,
    float* __restrict__ h, int* __restrict__ donep,
    int* __restrict__ cnt,
    const float* __restrict__ betap, float mean_w)
{
  if (*donep) return;
  const int t = threadIdx.x, g = t>>4, q = t&15;
  __shared__ float sm[16][17];
  {
    const int base = blockIdx.x*256;
    const int lim = min(base+256, nrows);
    float s = 0.0f;
    for (int r = base+g; r < lim; r += 16) s += hpart[(size_t)r*Q + q];
    sm[g][q] = s; __syncthreads();
    if (t < Q){
      float tot = 0.0f;
      #pragma unroll
      for (int i=0;i<16;i++) tot += sm[i][t];
      hpart2[(size_t)blockIdx.x*Q + t] = tot;
    }
  }
  __shared__ int amLast;
  __threadfence();
  if (t == 0) amLast = (atomicAdd(cnt, 1) == gH-1);
  __syncthreads();
  if (!amLast) return;
  {
    float s = 0.0f;
    for (int b = g; b < gH; b += 16) s += hpart2[(size_t)b*Q + q];
    __syncthreads();
    sm[g][q] = s; __syncthreads();
    if (t < Q){
      float tot = 0.0f;
      #pragma unroll
      for (int i=0;i<16;i++) tot += sm[i][t];
      h[t] = -(*betap) * mean_w * tot;
    }
  }
  float m = 0.0f;
  for (int i = t; i < nbd; i += 256) m = fmaxf(m, diffpart[i]);
  m = wmaxr(m);
  __shared__ float red[4];
  if ((t & 63) == 0) red[t>>6] = m;
  __syncthreads();
  if (t == 0 &&
      fmaxf(fmaxf(red[0],red[1]), fmaxf(red[2],red[3])) < 0.01f) *donep = 1;
}

// ---- h partials over psi0 (init only) ----
__global__ void __launch_bounds__(256) k_h_part(
    const float* __restrict__ psi, float* __restrict__ hpart, int N)
{
  const int n = blockIdx.x*blockDim.x + threadIdx.x;
  float pv[Q];
  if (n < N) {
    const float4* a = (const float4*)(psi + (size_t)n*Q);
    #pragma unroll
    for (int i=0;i<4;i++){ float4 t=a[i]; pv[4*i]=t.x; pv[4*i+1]=t.y; pv[4*i+2]=t.z; pv[4*i+3]=t.w; }
  } else {
    #pragma unroll
    for (int q=0;q<Q;q++) pv[q]=0.0f;
  }
  __shared__ float sm[4][Q];
  const int wid = threadIdx.x>>6, lane = threadIdx.x&63;
  #pragma unroll
  for (int q=0;q<Q;q++){
    float s = wsum(pv[q]);
    if (lane == 0) sm[wid][q] = s;
  }
  __syncthreads();
  if (threadIdx.x < Q)
    hpart[(size_t)blockIdx.x*Q + threadIdx.x] =
      sm[0][threadIdx.x]+sm[1][threadIdx.x]+sm[2][threadIdx.x]+sm[3][threadIdx.x];
}

__global__ void __launch_bounds__(256) k_hfin(
    const float* __restrict__ hpart, float* __restrict__ h,
    const float* __restrict__ betap, int nb, float mean_w)
{
  const int t = threadIdx.x, g = t>>4, q = t&15;
  float s = 0.0f;
  for (int b = g; b < nb; b += 16) s += hpart[(size_t)b*Q + q];
  __shared__ float sm[16][17];
  sm[g][q] = s; __syncthreads();
  if (t < Q){
    float tot = 0.0f;
    #pragma unroll
    for (int i=0;i<16;i++) tot += sm[i][t];
    h[t] = -(*betap) * mean_w * tot;
  }
}

// ---- CSR build ----
__global__ void __launch_bounds__(256) k_deg(
    const int* __restrict__ dst, int* __restrict__ deg, int E)
{
  const int e = blockIdx.x*blockDim.x + threadIdx.x;
  if (e < E) atomicAdd(&deg[dst[e]], 1);
}

__global__ void __launch_bounds__(SCAN_B) k_scan1(
    const int* __restrict__ deg, int* __restrict__ offs,
    int* __restrict__ bsum, int N)
{
  __shared__ int sm[SCAN_B];
  const int i = blockIdx.x*SCAN_B + threadIdx.x;
  const int v = (i<N) ? deg[i] : 0;
  sm[threadIdx.x] = v; __syncthreads();
  #pragma unroll
  for (int o=1;o<SCAN_B;o<<=1){
    int t = (threadIdx.x>=o) ? sm[threadIdx.x-o] : 0;
    __syncthreads();
    sm[threadIdx.x] += t;
    __syncthreads();
  }
  if (i<N) offs[i] = sm[threadIdx.x] - v;           // block-local exclusive
  if (threadIdx.x==SCAN_B-1) bsum[blockIdx.x] = sm[threadIdx.x];
}

__global__ void __launch_bounds__(SCAN_B) k_scan2(int* __restrict__ bsum, int nb)
{
  __shared__ int sm[SCAN_B];
  const int v = (threadIdx.x<nb) ? bsum[threadIdx.x] : 0;
  sm[threadIdx.x] = v; __syncthreads();
  #pragma unroll
  for (int o=1;o<SCAN_B;o<<=1){
    int t = (threadIdx.x>=o) ? sm[threadIdx.x-o] : 0;
    __syncthreads();
    sm[threadIdx.x] += t;
    __syncthreads();
  }
  if (threadIdx.x<nb) bsum[threadIdx.x] = sm[threadIdx.x] - v;  // exclusive
}

__global__ void __launch_bounds__(SCAN_B) k_scan3(
    int* __restrict__ offs, int* __restrict__ cursor,
    const int* __restrict__ bsum, int N, int E)
{
  const int i = blockIdx.x*SCAN_B + threadIdx.x;
  if (i<N){
    const int o = offs[i] + bsum[blockIdx.x];
    offs[i] = o; cursor[i] = o;
  }
  if (i==0) offs[N] = E;
}

__global__ void __launch_bounds__(256) k_fill(
    const int* __restrict__ dst, int* __restrict__ cursor,
    int* __restrict__ eid, int E)
{
  const int e = blockIdx.x*blockDim.x + threadIdx.x;
  if (e < E){
    const int p = atomicAdd(&cursor[dst[e]], 1);
    eid[p] = e;
  }
}

// ---- fused finalization (R11/R12-validated): 256 blocks, 1 fence each ----
__global__ void __launch_bounds__(256) k_stats(
    const int* __restrict__ src, const int* __restrict__ dst,
    const float* __restrict__ psi, const int* __restrict__ deg,
    float* __restrict__ colpart, float* __restrict__ degpart,
    float* __restrict__ entpart, float* __restrict__ edgepart,
    int* __restrict__ cnt, float* __restrict__ out,
    int M, int N, int NQ, float m2, int gS)
{
  const int t = threadIdx.x;
  const int lane = t & 63, wid = t >> 6;
  float ed = 0.0f;
  for (int p = blockIdx.x*256 + t; p < M; p += gS*256){
    const int u = src[p], v = dst[p];
    const float4* a = (const float4*)(psi + (size_t)u*Q);
    const float4* b = (const float4*)(psi + (size_t)v*Q);
    float d = 0.0f;
    #pragma unroll
    for (int i=0;i<4;i++){
      float4 x=a[i], y=b[i];
      d += x.x*y.x + x.y*y.y + x.z*y.z + x.w*y.w;
    }
    ed += 2.0f*d;   // pair appears twice in directed list
  }
  float ca[Q], da[Q]; float ea = 0.0f;
  #pragma unroll
  for (int q=0;q<Q;q++){ ca[q]=0.0f; da[q]=0.0f; }
  for (int n = blockIdx.x*256 + t; n < N; n += gS*256){
    const float4* a = (const float4*)(psi + (size_t)n*Q);
    float pv[Q];
    #pragma unroll
    for (int i=0;i<4;i++){ float4 x=a[i]; pv[4*i]=x.x; pv[4*i+1]=x.y; pv[4*i+2]=x.z; pv[4*i+3]=x.w; }
    const float dg = (float)deg[n];
    #pragma unroll
    for (int q=0;q<Q;q++){
      ca[q] += pv[q];
      da[q] += pv[q]*dg;
      ea    -= pv[q]*__logf(pv[q]+1e-12f);
    }
  }
  __shared__ float smc[4][17], smd[4][17];
  __shared__ float sme[4], smeE[4];
  __shared__ float smg[16][17], smg2[16][17];
  __shared__ int amL;
  #pragma unroll
  for (int q=0;q<Q;q++){
    float s  = wsum(ca[q]);
    float s2 = wsum(da[q]);
    if (lane == 0){ smc[wid][q]=s; smd[wid][q]=s2; }
  }
  float se = wsum(ea);
  float sed = wsum(ed);
  if (lane == 0){ sme[wid]=se; smeE[wid]=sed; }
  __syncthreads();
  if (t < Q){
    colpart[(size_t)blockIdx.x*Q+t] = smc[0][t]+smc[1][t]+smc[2][t]+smc[3][t];
    degpart[(size_t)blockIdx.x*Q+t] = smd[0][t]+smd[1][t]+smd[2][t]+smd[3][t];
  }
  if (t == 0){
    entpart[blockIdx.x]  = sme[0]+sme[1]+sme[2]+sme[3];
    edgepart[blockIdx.x] = smeE[0]+smeE[1]+smeE[2]+smeE[3];
  }
  __threadfence();
  if (t == 0) amL = (atomicAdd(cnt, 1) == gS-1);
  __syncthreads();
  if (!amL) return;
  // last block: fold gS(=256) partial rows -> final scalars
  {
    const int g = t>>4, qq = t&15;
    float cs=0.0f, ds=0.0f;
    for (int r = g; r < gS; r += 16){
      cs += colpart[(size_t)r*Q + qq];
      ds += degpart[(size_t)r*Q + qq];
    }
    smg[g][qq] = cs; smg2[g][qq] = ds;
    __syncthreads();
    float colq=0.0f, degq=0.0f;
    if (t < Q){
      #pragma unroll
      for (int i=0;i<16;i++){ colq += smg[i][t]; degq += smg2[i][t]; }
    }
    float es=0.0f, en=0.0f;
    for (int i=t; i<gS; i+=256){ es += edgepart[i]; en += entpart[i]; }
    es = wsum(es); en = wsum(en);
    if (lane == 0){ smeE[wid]=es; sme[wid]=en; }
    __syncthreads();
    if (t < Q){ smg[0][t] = colq; smg2[0][t] = degq; }
    __syncthreads();
    if (t == 0){
      const float edge_total = smeE[0]+smeE[1]+smeE[2]+smeE[3];
      const float ent_total  = sme[0]+sme[1]+sme[2]+sme[3];
      float reg = 0.0f, dt = 0.0f;
      for (int i=0;i<Q;i++){
        float d = smg[0][i]/(float)N - 1.0f/(float)Q; reg += d*d;
        float s = smg2[0][i]/m2; dt += s*s;
      }
      out[NQ+0] = reg * 4.0f;                                // * sqrt(16)
      out[NQ+1] = ent_total/(float)N / 2.7725887222397811f;  // / log(16)
      out[NQ+2] = edge_total/m2 - dt;
    }
  }
}

extern "C" void kernel_launch(void* const* d_in, const int* in_sizes, int n_in,
                              void* d_out, int out_size, void* d_ws, size_t ws_size,
                              hipStream_t stream)
{
  const int*   src   = (const int*)  d_in[0];
  const int*   dst   = (const int*)  d_in[1];
  // d_in[2] = rev : structurally rev[p]=p+M / p-M, exploited directly
  const float* psi0  = (const float*)d_in[3];
  const float* msg0  = (const float*)d_in[4];
  const float* betap = (const float*)d_in[5];

  const int E  = in_sizes[0];
  const int M  = E/2;
  const int NQ = in_sizes[3];
  const int N  = NQ/Q;
  const float mean_w = (float)((double)E/((double)N*(double)N));
  const float m2 = (float)E;

  const int B = 256;
  const int gE = (E+B-1)/B, gN = (N+B-1)/B;
  const int nb = (N+SCAN_B-1)/SCAN_B;
  const int nbE = 2048;                          // edge grid (grid-stride)
  const int gW = (N+3)/4;                        // gather: one wave per node
  const int gH = (gW+255)/256;                   // hred blocks (~49)
  const int gS = 256;                            // stats grid
  const int HPROWS = (gW > gN ? gW : gN);

  char* w = (char*)d_ws;
  float* msgA    = (float*)w; w += (size_t)E*Q*sizeof(float);
  float* nl      = (float*)w; w += (size_t)NQ*sizeof(float);
  int*   eid     = (int*)  w; w += (size_t)E*sizeof(int);
  int*   offs    = (int*)  w; w += (size_t)(N+16)*sizeof(int);
  int*   cursor  = (int*)  w; w += (size_t)(N+16)*sizeof(int);
  int*   bsum    = (int*)  w; w += 256*sizeof(int);
  float* hpart   = (float*)w; w += (size_t)HPROWS*Q*sizeof(float);
  float* hpart2  = (float*)w; w += (size_t)(gH+4)*Q*sizeof(float);
  float* diffpart= (float*)w; w += (size_t)nbE*sizeof(float);
  float* edgepart= (float*)w; w += (size_t)gS*sizeof(float);
  float* colpart = (float*)w; w += (size_t)gS*Q*sizeof(float);
  float* degpart = (float*)w; w += (size_t)gS*Q*sizeof(float);
  float* entpart = (float*)w; w += (size_t)gS*sizeof(float);
  int*   deg     = (int*)  w; w += (size_t)(N+16)*sizeof(int);   // memset from here
  float* h       = (float*)w; w += 16*sizeof(float);
  int*   donep   = (int*)  w; w += 4*sizeof(int);
  int*   cnt     = (int*)  w; w += 16*sizeof(int);               // per-iter arrival counters
  int*   cnts    = (int*)  w; w += 4*sizeof(int);                // stats counter

  float* psi = (float*)d_out;   // [N,Q]; scalars at NQ..NQ+2

  const size_t small_bytes = (size_t)((char*)w - (char*)deg);
  hipMemsetAsync(deg, 0, small_bytes, stream);   // deg, h, done, counters

  // one-time: h0, CSR build (eid), initial node_log
  k_h_part<<<gN,B,0,stream>>>(psi0, hpart, N);
  k_hfin  <<<1, B,0,stream>>>(hpart, h, betap, gN, mean_w);
  k_deg   <<<gE,B,0,stream>>>(dst, deg, E);
  k_scan1 <<<nb,SCAN_B,0,stream>>>(deg, offs, bsum, N);
  k_scan2 <<<1, SCAN_B,0,stream>>>(bsum, nb);
  k_scan3 <<<nb,SCAN_B,0,stream>>>(offs, cursor, bsum, N, E);
  k_fill  <<<gE,B,0,stream>>>(dst, cursor, eid, E);
  k_gather<<<gW,B,0,stream>>>(msg0, offs, eid, nl, h, psi, betap, donep,
                              hpart, N, 0);

  for (int k=0; k<10; ++k) {
    const float* mc = (k==0) ? msg0 : msgA;
    k_edge16<<<nbE,B,0,stream>>>(src, dst, mc, msgA, nl, h, betap,
                                 diffpart, donep, M);
    k_gather<<<gW,B,0,stream>>>(msgA, offs, eid, nl, h, psi, betap, donep,
                                hpart, N, 1);
    k_hred2 <<<gH,B,0,stream>>>(hpart, gW, hpart2, gH, diffpart, nbE,
                                h, donep, &cnt[k], betap, mean_w);
  }

  k_stats<<<gS,B,0,stream>>>(src, dst, psi, deg, colpart, degpart,
                             entpart, edgepart, cnts, psi, M, N, NQ, m2, gS);
}

// Round 14
// 968.567 us; speedup vs baseline: 1.1188x; 1.1188x over previous
//
#include <hip/hip_runtime.h>

#define Q 16
#define SCAN_B 256

__device__ __forceinline__ float wsum(float v){
  #pragma unroll
  for(int o=32;o;o>>=1) v += __shfl_xor(v,o);
  return v;
}
__device__ __forceinline__ float wmaxr(float v){
  #pragma unroll
  for(int o=32;o;o>>=1) v = fmaxf(v,__shfl_xor(v,o));
  return v;
}

// ---- edge kernel with fused h/done prologue (2-dispatch loop) ----
// Prologue: fold hpart2[k-1] (196x16 raw psi col sums, 12.5KB L2) -> h_k;
// fold diffpart[k-1] (8KB) -> done decision. Kernel-boundary ordering makes
// this fence-free (R11 lesson: per-block fences at 12500 blocks = disaster).
__global__ void __launch_bounds__(256, 4) k_edgeF(
    const int* __restrict__ src, const int* __restrict__ dst,
    const int* __restrict__ ipos,
    float* msgC, const float* __restrict__ nl,
    const float* __restrict__ betap,
    const float* __restrict__ hsrc, int nch,
    const float* __restrict__ diffprev, int nbd,
    float* __restrict__ diffout, float* __restrict__ hout,
    int* __restrict__ donep, int M, float mean_w, int k)
{
  if (*donep) return;
  const float beta = *betap;
  const float eb = __expf(beta) - 1.0f;
  const int t = threadIdx.x;
  __shared__ float smf[16][17];
  __shared__ float hq_sm[16];
  __shared__ float smx[4];
  __shared__ int brk;
  {
    const int g = t>>4, qq = t&15;
    float s = 0.0f;
    for (int r = g; r < nch; r += 16) s += hsrc[(size_t)r*Q + qq];
    smf[g][qq] = s; __syncthreads();
    if (t < Q){
      float tot = 0.0f;
      #pragma unroll
      for (int i=0;i<16;i++) tot += smf[i][t];
      hq_sm[t] = -beta * mean_w * tot;
    }
  }
  if (k > 0){
    float dm = 0.0f;
    for (int i = t; i < nbd; i += 256) dm = fmaxf(dm, diffprev[i]);
    dm = wmaxr(dm);
    if ((t & 63) == 0) smx[t>>6] = dm;
    __syncthreads();
    if (t == 0)
      brk = (fmaxf(fmaxf(smx[0],smx[1]), fmaxf(smx[2],smx[3])) < 0.01f);
    __syncthreads();
    if (brk){ if (blockIdx.x == 0 && t == 0) *donep = 1; return; }
  } else {
    __syncthreads();
  }
  if (blockIdx.x == 0 && t < Q) hout[t] = hq_sm[t];
  const float hq = hq_sm[t & 15];

  // ---- main pair loop (R12-proven form: 16 lanes/pair, x2 unroll) ----
  const int q = t & 15;
  const int grp  = (blockIdx.x*blockDim.x + t) >> 4;
  const int ngrp = (gridDim.x*blockDim.x) >> 4;
  float dloc = 0.0f;
  int p = grp;
  for (; p + ngrp < M; p += 2*ngrp){
    const int pA = p, pB = p + ngrp;
    const int uA = src[pA], vA = dst[pA];
    const int uB = src[pB], vB = dst[pB];
    const int a0 = ipos[pA], a1 = ipos[pA + M];
    const int b0 = ipos[pB], b1 = ipos[pB + M];
    const float mA0 = msgC[(size_t)a0*Q + q], mA1 = msgC[(size_t)a1*Q + q];
    const float mB0 = msgC[(size_t)b0*Q + q], mB1 = msgC[(size_t)b1*Q + q];
    const float nuA = nl[(size_t)uA*Q + q],  nvA = nl[(size_t)vA*Q + q];
    const float nuB = nl[(size_t)uB*Q + q],  nvB = nl[(size_t)vB*Q + q];
    float tA0 = nuA - __logf(fmaf(mA1, eb, 1.0f)) + hq;
    float tA1 = nvA - __logf(fmaf(mA0, eb, 1.0f)) + hq;
    float tB0 = nuB - __logf(fmaf(mB1, eb, 1.0f)) + hq;
    float tB1 = nvB - __logf(fmaf(mB0, eb, 1.0f)) + hq;
    float xA0=tA0, xA1=tA1, xB0=tB0, xB1=tB1;
    #pragma unroll
    for (int o=1;o<16;o<<=1){
      xA0=fmaxf(xA0,__shfl_xor(xA0,o)); xA1=fmaxf(xA1,__shfl_xor(xA1,o));
      xB0=fmaxf(xB0,__shfl_xor(xB0,o)); xB1=fmaxf(xB1,__shfl_xor(xB1,o));
    }
    const float eA0=__expf(tA0-xA0), eA1=__expf(tA1-xA1);
    const float eB0=__expf(tB0-xB0), eB1=__expf(tB1-xB1);
    float sA0=eA0, sA1=eA1, sB0=eB0, sB1=eB1;
    #pragma unroll
    for (int o=1;o<16;o<<=1){
      sA0+=__shfl_xor(sA0,o); sA1+=__shfl_xor(sA1,o);
      sB0+=__shfl_xor(sB0,o); sB1+=__shfl_xor(sB1,o);
    }
    const float nA0=eA0/sA0, nA1=eA1/sA1, nB0=eB0/sB0, nB1=eB1/sB1;
    float dA0=fabsf(nA0-mA0), dA1=fabsf(nA1-mA1);
    float dB0=fabsf(nB0-mB0), dB1=fabsf(nB1-mB1);
    #pragma unroll
    for (int o=1;o<16;o<<=1){
      dA0+=__shfl_xor(dA0,o); dA1+=__shfl_xor(dA1,o);
      dB0+=__shfl_xor(dB0,o); dB1+=__shfl_xor(dB1,o);
    }
    dloc = fmaxf(dloc, fmaxf(fmaxf(dA0,dA1), fmaxf(dB0,dB1)));
    msgC[(size_t)a0*Q + q] = nA0;  msgC[(size_t)a1*Q + q] = nA1;
    msgC[(size_t)b0*Q + q] = nB0;  msgC[(size_t)b1*Q + q] = nB1;
  }
  if (p < M){
    const int u = src[p], v = dst[p];
    const int i0 = ipos[p], i1 = ipos[p + M];
    const float m0 = msgC[(size_t)i0*Q + q], m1 = msgC[(size_t)i1*Q + q];
    const float nu = nl[(size_t)u*Q + q],   nv = nl[(size_t)v*Q + q];
    float t0 = nu - __logf(fmaf(m1, eb, 1.0f)) + hq;
    float t1 = nv - __logf(fmaf(m0, eb, 1.0f)) + hq;
    float x0=t0, x1=t1;
    #pragma unroll
    for (int o=1;o<16;o<<=1){
      x0=fmaxf(x0,__shfl_xor(x0,o)); x1=fmaxf(x1,__shfl_xor(x1,o));
    }
    const float e0=__expf(t0-x0), e1=__expf(t1-x1);
    float s0=e0, s1=e1;
    #pragma unroll
    for (int o=1;o<16;o<<=1){ s0+=__shfl_xor(s0,o); s1+=__shfl_xor(s1,o); }
    const float n0=e0/s0, n1=e1/s1;
    float d0=fabsf(n0-m0), d1=fabsf(n1-m1);
    #pragma unroll
    for (int o=1;o<16;o<<=1){ d0+=__shfl_xor(d0,o); d1+=__shfl_xor(d1,o); }
    dloc = fmaxf(dloc, fmaxf(d0,d1));
    msgC[(size_t)i0*Q + q] = n0;  msgC[(size_t)i1*Q + q] = n1;
  }
  float wm = wmaxr(dloc);
  if ((t & 63) == 0) smx[t>>6] = wm;
  __syncthreads();
  if (t == 0)
    diffout[blockIdx.x] = fmaxf(fmaxf(smx[0],smx[1]), fmaxf(smx[2],smx[3]));
}

// ---- gather: one wave per node, contiguous CSR rows (R12-proven), h from
// harr[k] (published by edge block 0), psi col-sums via chunked atomics
// (64 blocks/chunk -> ~64 same-address adds; R2 lesson: never same-line pileup)
__global__ void __launch_bounds__(256, 4) k_gatherF2(
    const float* __restrict__ msgC, const int* __restrict__ offs,
    float* __restrict__ nl, const float* __restrict__ hk,
    float* __restrict__ psi, const float* __restrict__ betap,
    const int* __restrict__ donep, float* __restrict__ hp2k,
    int N, int mode)
{
  if (mode && *donep) return;
  const int wid = threadIdx.x >> 6;                 // 0..3
  const int n = blockIdx.x*4 + wid;
  const float eb = __expf(*betap) - 1.0f;
  const int lane = threadIdx.x & 63;
  const int sub = lane >> 4, q16 = lane & 15;
  int start = 0, end = 0;
  if (n < N){ start = offs[n]; end = offs[n+1]; }
  float acc = 0.0f;
  int i = start + sub;
  for (; i + 4 < end; i += 8){
    const float x0 = msgC[(size_t)i*Q + q16];
    const float x1 = msgC[(size_t)(i+4)*Q + q16];
    acc += __logf(fmaf(x0, eb, 1.0f)) + __logf(fmaf(x1, eb, 1.0f));
  }
  if (i < end) acc += __logf(fmaf(msgC[(size_t)i*Q + q16], eb, 1.0f));
  acc += __shfl_xor(acc, 16);
  acc += __shfl_xor(acc, 32);
  if (n < N && sub == 0) nl[(size_t)n*Q + q16] = acc;
  if (!mode) return;
  float t = acc + hk[q16];
  float m = t;
  #pragma unroll
  for (int o=1;o<16;o<<=1) m = fmaxf(m, __shfl_xor(m,o));
  float ex = __expf(t-m);
  float s = ex;
  #pragma unroll
  for (int o=1;o<16;o<<=1) s += __shfl_xor(s,o);
  const float pq = ex/s;
  if (n < N && sub == 0) psi[(size_t)n*Q + q16] = pq;
  __shared__ float smh[4][17];
  if (sub == 0) smh[wid][q16] = (n < N) ? pq : 0.0f;
  __syncthreads();
  if (threadIdx.x < Q)
    unsafeAtomicAdd(&hp2k[(size_t)(blockIdx.x>>6)*Q + threadIdx.x],
      smh[0][threadIdx.x]+smh[1][threadIdx.x]+smh[2][threadIdx.x]+smh[3][threadIdx.x]);
}

// ---- h partials over psi0 (init; edge_0 folds these rows directly) ----
__global__ void __launch_bounds__(256) k_h_part(
    const float* __restrict__ psi, float* __restrict__ hpart, int N)
{
  const int n = blockIdx.x*blockDim.x + threadIdx.x;
  float pv[Q];
  if (n < N) {
    const float4* a = (const float4*)(psi + (size_t)n*Q);
    #pragma unroll
    for (int i=0;i<4;i++){ float4 t=a[i]; pv[4*i]=t.x; pv[4*i+1]=t.y; pv[4*i+2]=t.z; pv[4*i+3]=t.w; }
  } else {
    #pragma unroll
    for (int q=0;q<Q;q++) pv[q]=0.0f;
  }
  __shared__ float sm[4][Q];
  const int wid = threadIdx.x>>6, lane = threadIdx.x&63;
  #pragma unroll
  for (int q=0;q<Q;q++){
    float s = wsum(pv[q]);
    if (lane == 0) sm[wid][q] = s;
  }
  __syncthreads();
  if (threadIdx.x < Q)
    hpart[(size_t)blockIdx.x*Q + threadIdx.x] =
      sm[0][threadIdx.x]+sm[1][threadIdx.x]+sm[2][threadIdx.x]+sm[3][threadIdx.x];
}

// ---- CSR build ----
__global__ void __launch_bounds__(256) k_deg(
    const int* __restrict__ dst, int* __restrict__ deg, int E)
{
  const int e = blockIdx.x*blockDim.x + threadIdx.x;
  if (e < E) atomicAdd(&deg[dst[e]], 1);
}

__global__ void __launch_bounds__(SCAN_B) k_scan1(
    const int* __restrict__ deg, int* __restrict__ offs,
    int* __restrict__ bsum, int N)
{
  __shared__ int sm[SCAN_B];
  const int i = blockIdx.x*SCAN_B + threadIdx.x;
  const int v = (i<N) ? deg[i] : 0;
  sm[threadIdx.x] = v; __syncthreads();
  #pragma unroll
  for (int o=1;o<SCAN_B;o<<=1){
    int t = (threadIdx.x>=o) ? sm[threadIdx.x-o] : 0;
    __syncthreads();
    sm[threadIdx.x] += t;
    __syncthreads();
  }
  if (i<N) offs[i] = sm[threadIdx.x] - v;           // block-local exclusive
  if (threadIdx.x==SCAN_B-1) bsum[blockIdx.x] = sm[threadIdx.x];
}

__global__ void __launch_bounds__(SCAN_B) k_scan2(int* __restrict__ bsum, int nb)
{
  __shared__ int sm[SCAN_B];
  const int v = (threadIdx.x<nb) ? bsum[threadIdx.x] : 0;
  sm[threadIdx.x] = v; __syncthreads();
  #pragma unroll
  for (int o=1;o<SCAN_B;o<<=1){
    int t = (threadIdx.x>=o) ? sm[threadIdx.x-o] : 0;
    __syncthreads();
    sm[threadIdx.x] += t;
    __syncthreads();
  }
  if (threadIdx.x<nb) bsum[threadIdx.x] = sm[threadIdx.x] - v;  // exclusive
}

__global__ void __launch_bounds__(SCAN_B) k_scan3(
    int* __restrict__ offs, int* __restrict__ cursor,
    const int* __restrict__ bsum, int N, int E)
{
  const int i = blockIdx.x*SCAN_B + threadIdx.x;
  if (i<N){
    const int o = offs[i] + bsum[blockIdx.x];
    offs[i] = o; cursor[i] = o;
  }
  if (i==0) offs[N] = E;
}

// ---- fused fill + scatter: ipos[e] = CSR slot; msgC[slot] = msg0[e] ----
__global__ void __launch_bounds__(256) k_fillCS(
    const int* __restrict__ dst, int* __restrict__ cursor,
    const float* __restrict__ msg0, float* __restrict__ msgC,
    int* __restrict__ ipos, int E)
{
  const int e = blockIdx.x*blockDim.x + threadIdx.x;
  if (e >= E) return;
  const int ip = atomicAdd(&cursor[dst[e]], 1);
  ipos[e] = ip;
  const float4* s = (const float4*)(msg0 + (size_t)e*Q);
  float4* d = (float4*)(msgC + (size_t)ip*Q);
  float4 x0=s[0], x1=s[1], x2=s[2], x3=s[3];
  d[0]=x0; d[1]=x1; d[2]=x2; d[3]=x3;
}

// ---- fused finalization (R11/R12-validated): 256 blocks, 1 fence each ----
__global__ void __launch_bounds__(256) k_stats(
    const int* __restrict__ src, const int* __restrict__ dst,
    const float* __restrict__ psi, const int* __restrict__ deg,
    float* __restrict__ colpart, float* __restrict__ degpart,
    float* __restrict__ entpart, float* __restrict__ edgepart,
    int* __restrict__ cnt, float* __restrict__ out,
    int M, int N, int NQ, float m2, int gS)
{
  const int t = threadIdx.x;
  const int lane = t & 63, wid = t >> 6;
  float ed = 0.0f;
  for (int p = blockIdx.x*256 + t; p < M; p += gS*256){
    const int u = src[p], v = dst[p];
    const float4* a = (const float4*)(psi + (size_t)u*Q);
    const float4* b = (const float4*)(psi + (size_t)v*Q);
    float d = 0.0f;
    #pragma unroll
    for (int i=0;i<4;i++){
      float4 x=a[i], y=b[i];
      d += x.x*y.x + x.y*y.y + x.z*y.z + x.w*y.w;
    }
    ed += 2.0f*d;   // pair appears twice in directed list
  }
  float ca[Q], da[Q]; float ea = 0.0f;
  #pragma unroll
  for (int q=0;q<Q;q++){ ca[q]=0.0f; da[q]=0.0f; }
  for (int n = blockIdx.x*256 + t; n < N; n += gS*256){
    const float4* a = (const float4*)(psi + (size_t)n*Q);
    float pv[Q];
    #pragma unroll
    for (int i=0;i<4;i++){ float4 x=a[i]; pv[4*i]=x.x; pv[4*i+1]=x.y; pv[4*i+2]=x.z; pv[4*i+3]=x.w; }
    const float dg = (float)deg[n];
    #pragma unroll
    for (int q=0;q<Q;q++){
      ca[q] += pv[q];
      da[q] += pv[q]*dg;
      ea    -= pv[q]*__logf(pv[q]+1e-12f);
    }
  }
  __shared__ float smc[4][17], smd[4][17];
  __shared__ float sme[4], smeE[4];
  __shared__ float smg[16][17], smg2[16][17];
  __shared__ int amL;
  #pragma unroll
  for (int q=0;q<Q;q++){
    float s  = wsum(ca[q]);
    float s2 = wsum(da[q]);
    if (lane == 0){ smc[wid][q]=s; smd[wid][q]=s2; }
  }
  float se = wsum(ea);
  float sed = wsum(ed);
  if (lane == 0){ sme[wid]=se; smeE[wid]=sed; }
  __syncthreads();
  if (t < Q){
    colpart[(size_t)blockIdx.x*Q+t] = smc[0][t]+smc[1][t]+smc[2][t]+smc[3][t];
    degpart[(size_t)blockIdx.x*Q+t] = smd[0][t]+smd[1][t]+smd[2][t]+smd[3][t];
  }
  if (t == 0){
    entpart[blockIdx.x]  = sme[0]+sme[1]+sme[2]+sme[3];
    edgepart[blockIdx.x] = smeE[0]+smeE[1]+smeE[2]+smeE[3];
  }
  __threadfence();
  if (t == 0) amL = (atomicAdd(cnt, 1) == gS-1);
  __syncthreads();
  if (!amL) return;
  {
    const int g = t>>4, qq = t&15;
    float cs=0.0f, ds=0.0f;
    for (int r = g; r < gS; r += 16){
      cs += colpart[(size_t)r*Q + qq];
      ds += degpart[(size_t)r*Q + qq];
    }
    smg[g][qq] = cs; smg2[g][qq] = ds;
    __syncthreads();
    float colq=0.0f, degq=0.0f;
    if (t < Q){
      #pragma unroll
      for (int i=0;i<16;i++){ colq += smg[i][t]; degq += smg2[i][t]; }
    }
    float es=0.0f, en=0.0f;
    for (int i=t; i<gS; i+=256){ es += edgepart[i]; en += entpart[i]; }
    es = wsum(es); en = wsum(en);
    if (lane == 0){ smeE[wid]=es; sme[wid]=en; }
    __syncthreads();
    if (t < Q){ smg[0][t] = colq; smg2[0][t] = degq; }
    __syncthreads();
    if (t == 0){
      const float edge_total = smeE[0]+smeE[1]+smeE[2]+smeE[3];
      const float ent_total  = sme[0]+sme[1]+sme[2]+sme[3];
      float reg = 0.0f, dt = 0.0f;
      for (int i=0;i<Q;i++){
        float d = smg[0][i]/(float)N - 1.0f/(float)Q; reg += d*d;
        float s = smg2[0][i]/m2; dt += s*s;
      }
      out[NQ+0] = reg * 4.0f;                                // * sqrt(16)
      out[NQ+1] = ent_total/(float)N / 2.7725887222397811f;  // / log(16)
      out[NQ+2] = edge_total/m2 - dt;
    }
  }
}

extern "C" void kernel_launch(void* const* d_in, const int* in_sizes, int n_in,
                              void* d_out, int out_size, void* d_ws, size_t ws_size,
                              hipStream_t stream)
{
  const int*   src   = (const int*)  d_in[0];
  const int*   dst   = (const int*)  d_in[1];
  // d_in[2] = rev : structurally rev[p]=p+M / p-M, exploited directly
  const float* psi0  = (const float*)d_in[3];
  const float* msg0  = (const float*)d_in[4];
  const float* betap = (const float*)d_in[5];

  const int E  = in_sizes[0];
  const int M  = E/2;
  const int NQ = in_sizes[3];
  const int N  = NQ/Q;
  const float mean_w = (float)((double)E/((double)N*(double)N));
  const float m2 = (float)E;

  const int B = 256;
  const int gE = (E+B-1)/B, gN = (N+B-1)/B;
  const int nb = (N+SCAN_B-1)/SCAN_B;
  const int nbE = 2048;                          // edge grid (grid-stride)
  const int gW = (N+3)/4;                        // gather: one wave per node
  const int nchG = (gW+63)>>6;                   // gather h-chunks (~196)
  const int gS = 256;                            // stats grid

  char* w = (char*)d_ws;
  float* msgC    = (float*)w; w += (size_t)E*Q*sizeof(float);
  float* nl      = (float*)w; w += (size_t)NQ*sizeof(float);
  int*   ipos    = (int*)  w; w += (size_t)E*sizeof(int);
  int*   offs    = (int*)  w; w += (size_t)(N+16)*sizeof(int);
  int*   cursor  = (int*)  w; w += (size_t)(N+16)*sizeof(int);
  int*   bsum    = (int*)  w; w += 256*sizeof(int);
  float* hp0     = (float*)w; w += (size_t)gN*Q*sizeof(float);
  float* edgepart= (float*)w; w += (size_t)gS*sizeof(float);
  float* colpart = (float*)w; w += (size_t)gS*Q*sizeof(float);
  float* degpart = (float*)w; w += (size_t)gS*Q*sizeof(float);
  float* entpart = (float*)w; w += (size_t)gS*sizeof(float);
  int*   deg     = (int*)  w; w += (size_t)(N+16)*sizeof(int);   // memset from here
  float* hpart2  = (float*)w; w += (size_t)10*nchG*Q*sizeof(float);
  float* diffpart= (float*)w; w += (size_t)10*nbE*sizeof(float);
  float* harr    = (float*)w; w += (size_t)10*Q*sizeof(float);
  int*   donep   = (int*)  w; w += 4*sizeof(int);
  int*   cnts    = (int*)  w; w += 4*sizeof(int);

  float* psi = (float*)d_out;   // [N,Q]; scalars at NQ..NQ+2

  const size_t small_bytes = (size_t)((char*)w - (char*)deg);
  hipMemsetAsync(deg, 0, small_bytes, stream);   // deg, hpart2, diff, h, flags

  // one-time: psi0 partials, CSR build (ipos) + scatter msg0->msgC, nl_0
  k_h_part  <<<gN,B,0,stream>>>(psi0, hp0, N);
  k_deg     <<<gE,B,0,stream>>>(dst, deg, E);
  k_scan1   <<<nb,SCAN_B,0,stream>>>(deg, offs, bsum, N);
  k_scan2   <<<1, SCAN_B,0,stream>>>(bsum, nb);
  k_scan3   <<<nb,SCAN_B,0,stream>>>(offs, cursor, bsum, N, E);
  k_fillCS  <<<gE,B,0,stream>>>(dst, cursor, msg0, msgC, ipos, E);
  k_gatherF2<<<gW,B,0,stream>>>(msgC, offs, nl, harr, psi, betap, donep,
                                hpart2, N, 0);

  for (int k=0; k<10; ++k) {
    const float* hs  = (k==0) ? hp0 : (hpart2 + (size_t)(k-1)*nchG*Q);
    const int    nch = (k==0) ? gN : nchG;
    const float* dp  = diffpart + (size_t)(k>0 ? k-1 : 0)*nbE;
    k_edgeF   <<<nbE,B,0,stream>>>(src, dst, ipos, msgC, nl, betap,
                                   hs, nch, dp, nbE,
                                   diffpart + (size_t)k*nbE, harr + (size_t)k*Q,
                                   donep, M, mean_w, k);
    k_gatherF2<<<gW,B,0,stream>>>(msgC, offs, nl, harr + (size_t)k*Q, psi,
                                  betap, donep,
                                  hpart2 + (size_t)k*nchG*Q, N, 1);
  }

  k_stats<<<gS,B,0,stream>>>(src, dst, psi, deg, colpart, degpart,
                             entpart, edgepart, cnts, psi, M, N, NQ, m2, gS);
}

// Round 15
// 965.455 us; speedup vs baseline: 1.1224x; 1.0032x over previous
//
#include <hip/hip_runtime.h>

#define Q 16
#define SCAN_B 256

__device__ __forceinline__ float wsum(float v){
  #pragma unroll
  for(int o=32;o;o>>=1) v += __shfl_xor(v,o);
  return v;
}
__device__ __forceinline__ float wmaxr(float v){
  #pragma unroll
  for(int o=32;o;o>>=1) v = fmaxf(v,__shfl_xor(v,o));
  return v;
}

// ---- edge kernel with fused h/done prologue (2-dispatch loop) ----
// launch_bounds(256,8): VGPR=24 fits 8 waves/SIMD (32/CU) — double the
// in-flight random 64B requests vs the (256,4) cap carried since R6.
__global__ void __launch_bounds__(256, 8) k_edgeF(
    const int* __restrict__ src, const int* __restrict__ dst,
    const int* __restrict__ ipos,
    float* msgC, const float* __restrict__ nl,
    const float* __restrict__ betap,
    const float* __restrict__ hsrc, int nch,
    const float* __restrict__ diffprev, int nbd,
    float* __restrict__ diffout, float* __restrict__ hout,
    int* __restrict__ donep, int M, float mean_w, int k)
{
  if (*donep) return;
  const float beta = *betap;
  const float eb = __expf(beta) - 1.0f;
  const int t = threadIdx.x;
  __shared__ float smf[16][17];
  __shared__ float hq_sm[16];
  __shared__ float smx[4];
  __shared__ int brk;
  {
    const int g = t>>4, qq = t&15;
    float s = 0.0f;
    for (int r = g; r < nch; r += 16) s += hsrc[(size_t)r*Q + qq];
    smf[g][qq] = s; __syncthreads();
    if (t < Q){
      float tot = 0.0f;
      #pragma unroll
      for (int i=0;i<16;i++) tot += smf[i][t];
      hq_sm[t] = -beta * mean_w * tot;
    }
  }
  if (k > 0){
    float dm = 0.0f;
    for (int i = t; i < nbd; i += 256) dm = fmaxf(dm, diffprev[i]);
    dm = wmaxr(dm);
    if ((t & 63) == 0) smx[t>>6] = dm;
    __syncthreads();
    if (t == 0)
      brk = (fmaxf(fmaxf(smx[0],smx[1]), fmaxf(smx[2],smx[3])) < 0.01f);
    __syncthreads();
    if (brk){ if (blockIdx.x == 0 && t == 0) *donep = 1; return; }
  } else {
    __syncthreads();
  }
  if (blockIdx.x == 0 && t < Q) hout[t] = hq_sm[t];
  const float hq = hq_sm[t & 15];

  // ---- main pair loop (R12-proven form: 16 lanes/pair, x2 unroll) ----
  const int q = t & 15;
  const int grp  = (blockIdx.x*blockDim.x + t) >> 4;
  const int ngrp = (gridDim.x*blockDim.x) >> 4;
  float dloc = 0.0f;
  int p = grp;
  for (; p + ngrp < M; p += 2*ngrp){
    const int pA = p, pB = p + ngrp;
    const int uA = src[pA], vA = dst[pA];
    const int uB = src[pB], vB = dst[pB];
    const int a0 = ipos[pA], a1 = ipos[pA + M];
    const int b0 = ipos[pB], b1 = ipos[pB + M];
    const float mA0 = msgC[(size_t)a0*Q + q], mA1 = msgC[(size_t)a1*Q + q];
    const float mB0 = msgC[(size_t)b0*Q + q], mB1 = msgC[(size_t)b1*Q + q];
    const float nuA = nl[(size_t)uA*Q + q],  nvA = nl[(size_t)vA*Q + q];
    const float nuB = nl[(size_t)uB*Q + q],  nvB = nl[(size_t)vB*Q + q];
    float tA0 = nuA - __logf(fmaf(mA1, eb, 1.0f)) + hq;
    float tA1 = nvA - __logf(fmaf(mA0, eb, 1.0f)) + hq;
    float tB0 = nuB - __logf(fmaf(mB1, eb, 1.0f)) + hq;
    float tB1 = nvB - __logf(fmaf(mB0, eb, 1.0f)) + hq;
    float xA0=tA0, xA1=tA1, xB0=tB0, xB1=tB1;
    #pragma unroll
    for (int o=1;o<16;o<<=1){
      xA0=fmaxf(xA0,__shfl_xor(xA0,o)); xA1=fmaxf(xA1,__shfl_xor(xA1,o));
      xB0=fmaxf(xB0,__shfl_xor(xB0,o)); xB1=fmaxf(xB1,__shfl_xor(xB1,o));
    }
    const float eA0=__expf(tA0-xA0), eA1=__expf(tA1-xA1);
    const float eB0=__expf(tB0-xB0), eB1=__expf(tB1-xB1);
    float sA0=eA0, sA1=eA1, sB0=eB0, sB1=eB1;
    #pragma unroll
    for (int o=1;o<16;o<<=1){
      sA0+=__shfl_xor(sA0,o); sA1+=__shfl_xor(sA1,o);
      sB0+=__shfl_xor(sB0,o); sB1+=__shfl_xor(sB1,o);
    }
    const float nA0=eA0/sA0, nA1=eA1/sA1, nB0=eB0/sB0, nB1=eB1/sB1;
    float dA0=fabsf(nA0-mA0), dA1=fabsf(nA1-mA1);
    float dB0=fabsf(nB0-mB0), dB1=fabsf(nB1-mB1);
    #pragma unroll
    for (int o=1;o<16;o<<=1){
      dA0+=__shfl_xor(dA0,o); dA1+=__shfl_xor(dA1,o);
      dB0+=__shfl_xor(dB0,o); dB1+=__shfl_xor(dB1,o);
    }
    dloc = fmaxf(dloc, fmaxf(fmaxf(dA0,dA1), fmaxf(dB0,dB1)));
    msgC[(size_t)a0*Q + q] = nA0;  msgC[(size_t)a1*Q + q] = nA1;
    msgC[(size_t)b0*Q + q] = nB0;  msgC[(size_t)b1*Q + q] = nB1;
  }
  if (p < M){
    const int u = src[p], v = dst[p];
    const int i0 = ipos[p], i1 = ipos[p + M];
    const float m0 = msgC[(size_t)i0*Q + q], m1 = msgC[(size_t)i1*Q + q];
    const float nu = nl[(size_t)u*Q + q],   nv = nl[(size_t)v*Q + q];
    float t0 = nu - __logf(fmaf(m1, eb, 1.0f)) + hq;
    float t1 = nv - __logf(fmaf(m0, eb, 1.0f)) + hq;
    float x0=t0, x1=t1;
    #pragma unroll
    for (int o=1;o<16;o<<=1){
      x0=fmaxf(x0,__shfl_xor(x0,o)); x1=fmaxf(x1,__shfl_xor(x1,o));
    }
    const float e0=__expf(t0-x0), e1=__expf(t1-x1);
    float s0=e0, s1=e1;
    #pragma unroll
    for (int o=1;o<16;o<<=1){ s0+=__shfl_xor(s0,o); s1+=__shfl_xor(s1,o); }
    const float n0=e0/s0, n1=e1/s1;
    float d0=fabsf(n0-m0), d1=fabsf(n1-m1);
    #pragma unroll
    for (int o=1;o<16;o<<=1){ d0+=__shfl_xor(d0,o); d1+=__shfl_xor(d1,o); }
    dloc = fmaxf(dloc, fmaxf(d0,d1));
    msgC[(size_t)i0*Q + q] = n0;  msgC[(size_t)i1*Q + q] = n1;
  }
  float wm = wmaxr(dloc);
  if ((t & 63) == 0) smx[t>>6] = wm;
  __syncthreads();
  if (t == 0)
    diffout[blockIdx.x] = fmaxf(fmaxf(smx[0],smx[1]), fmaxf(smx[2],smx[3]));
}

// ---- gather: one wave per node, contiguous CSR rows, chunked-atomic h ----
__global__ void __launch_bounds__(256, 8) k_gatherF2(
    const float* __restrict__ msgC, const int* __restrict__ offs,
    float* __restrict__ nl, const float* __restrict__ hk,
    float* __restrict__ psi, const float* __restrict__ betap,
    const int* __restrict__ donep, float* __restrict__ hp2k,
    int N, int mode)
{
  if (mode && *donep) return;
  const int wid = threadIdx.x >> 6;                 // 0..3
  const int n = blockIdx.x*4 + wid;
  const float eb = __expf(*betap) - 1.0f;
  const int lane = threadIdx.x & 63;
  const int sub = lane >> 4, q16 = lane & 15;
  int start = 0, end = 0;
  if (n < N){ start = offs[n]; end = offs[n+1]; }
  float acc = 0.0f;
  int i = start + sub;
  for (; i + 4 < end; i += 8){
    const float x0 = msgC[(size_t)i*Q + q16];
    const float x1 = msgC[(size_t)(i+4)*Q + q16];
    acc += __logf(fmaf(x0, eb, 1.0f)) + __logf(fmaf(x1, eb, 1.0f));
  }
  if (i < end) acc += __logf(fmaf(msgC[(size_t)i*Q + q16], eb, 1.0f));
  acc += __shfl_xor(acc, 16);
  acc += __shfl_xor(acc, 32);
  if (n < N && sub == 0) nl[(size_t)n*Q + q16] = acc;
  if (!mode) return;
  float t = acc + hk[q16];
  float m = t;
  #pragma unroll
  for (int o=1;o<16;o<<=1) m = fmaxf(m, __shfl_xor(m,o));
  float ex = __expf(t-m);
  float s = ex;
  #pragma unroll
  for (int o=1;o<16;o<<=1) s += __shfl_xor(s,o);
  const float pq = ex/s;
  if (n < N && sub == 0) psi[(size_t)n*Q + q16] = pq;
  __shared__ float smh[4][17];
  if (sub == 0) smh[wid][q16] = (n < N) ? pq : 0.0f;
  __syncthreads();
  if (threadIdx.x < Q)
    unsafeAtomicAdd(&hp2k[(size_t)(blockIdx.x>>6)*Q + threadIdx.x],
      smh[0][threadIdx.x]+smh[1][threadIdx.x]+smh[2][threadIdx.x]+smh[3][threadIdx.x]);
}

// ---- h partials over psi0 (init; edge_0 folds these rows directly) ----
__global__ void __launch_bounds__(256, 8) k_h_part(
    const float* __restrict__ psi, float* __restrict__ hpart, int N)
{
  const int n = blockIdx.x*blockDim.x + threadIdx.x;
  float pv[Q];
  if (n < N) {
    const float4* a = (const float4*)(psi + (size_t)n*Q);
    #pragma unroll
    for (int i=0;i<4;i++){ float4 t=a[i]; pv[4*i]=t.x; pv[4*i+1]=t.y; pv[4*i+2]=t.z; pv[4*i+3]=t.w; }
  } else {
    #pragma unroll
    for (int q=0;q<Q;q++) pv[q]=0.0f;
  }
  __shared__ float sm[4][Q];
  const int wid = threadIdx.x>>6, lane = threadIdx.x&63;
  #pragma unroll
  for (int q=0;q<Q;q++){
    float s = wsum(pv[q]);
    if (lane == 0) sm[wid][q] = s;
  }
  __syncthreads();
  if (threadIdx.x < Q)
    hpart[(size_t)blockIdx.x*Q + threadIdx.x] =
      sm[0][threadIdx.x]+sm[1][threadIdx.x]+sm[2][threadIdx.x]+sm[3][threadIdx.x];
}

// ---- CSR build ----
__global__ void __launch_bounds__(256, 8) k_deg(
    const int* __restrict__ dst, int* __restrict__ deg, int E)
{
  const int e = blockIdx.x*blockDim.x + threadIdx.x;
  if (e < E) atomicAdd(&deg[dst[e]], 1);
}

__global__ void __launch_bounds__(SCAN_B) k_scan1(
    const int* __restrict__ deg, int* __restrict__ offs,
    int* __restrict__ bsum, int N)
{
  __shared__ int sm[SCAN_B];
  const int i = blockIdx.x*SCAN_B + threadIdx.x;
  const int v = (i<N) ? deg[i] : 0;
  sm[threadIdx.x] = v; __syncthreads();
  #pragma unroll
  for (int o=1;o<SCAN_B;o<<=1){
    int t = (threadIdx.x>=o) ? sm[threadIdx.x-o] : 0;
    __syncthreads();
    sm[threadIdx.x] += t;
    __syncthreads();
  }
  if (i<N) offs[i] = sm[threadIdx.x] - v;           // block-local exclusive
  if (threadIdx.x==SCAN_B-1) bsum[blockIdx.x] = sm[threadIdx.x];
}

__global__ void __launch_bounds__(SCAN_B) k_scan2(int* __restrict__ bsum, int nb)
{
  __shared__ int sm[SCAN_B];
  const int v = (threadIdx.x<nb) ? bsum[threadIdx.x] : 0;
  sm[threadIdx.x] = v; __syncthreads();
  #pragma unroll
  for (int o=1;o<SCAN_B;o<<=1){
    int t = (threadIdx.x>=o) ? sm[threadIdx.x-o] : 0;
    __syncthreads();
    sm[threadIdx.x] += t;
    __syncthreads();
  }
  if (threadIdx.x<nb) bsum[threadIdx.x] = sm[threadIdx.x] - v;  // exclusive
}

__global__ void __launch_bounds__(SCAN_B) k_scan3(
    int* __restrict__ offs, int* __restrict__ cursor,
    const int* __restrict__ bsum, int N, int E)
{
  const int i = blockIdx.x*SCAN_B + threadIdx.x;
  if (i<N){
    const int o = offs[i] + bsum[blockIdx.x];
    offs[i] = o; cursor[i] = o;
  }
  if (i==0) offs[N] = E;
}

// ---- fused fill + scatter: ipos[e] = CSR slot; msgC[slot] = msg0[e] ----
__global__ void __launch_bounds__(256, 8) k_fillCS(
    const int* __restrict__ dst, int* __restrict__ cursor,
    const float* __restrict__ msg0, float* __restrict__ msgC,
    int* __restrict__ ipos, int E)
{
  const int e = blockIdx.x*blockDim.x + threadIdx.x;
  if (e >= E) return;
  const int ip = atomicAdd(&cursor[dst[e]], 1);
  ipos[e] = ip;
  const float4* s = (const float4*)(msg0 + (size_t)e*Q);
  float4* d = (float4*)(msgC + (size_t)ip*Q);
  float4 x0=s[0], x1=s[1], x2=s[2], x3=s[3];
  d[0]=x0; d[1]=x1; d[2]=x2; d[3]=x3;
}

// ---- fused finalization (R11/R12-validated): 256 blocks, 1 fence each ----
__global__ void __launch_bounds__(256, 8) k_stats(
    const int* __restrict__ src, const int* __restrict__ dst,
    const float* __restrict__ psi, const int* __restrict__ deg,
    float* __restrict__ colpart, float* __restrict__ degpart,
    float* __restrict__ entpart, float* __restrict__ edgepart,
    int* __restrict__ cnt, float* __restrict__ out,
    int M, int N, int NQ, float m2, int gS)
{
  const int t = threadIdx.x;
  const int lane = t & 63, wid = t >> 6;
  float ed = 0.0f;
  for (int p = blockIdx.x*256 + t; p < M; p += gS*256){
    const int u = src[p], v = dst[p];
    const float4* a = (const float4*)(psi + (size_t)u*Q);
    const float4* b = (const float4*)(psi + (size_t)v*Q);
    float d = 0.0f;
    #pragma unroll
    for (int i=0;i<4;i++){
      float4 x=a[i], y=b[i];
      d += x.x*y.x + x.y*y.y + x.z*y.z + x.w*y.w;
    }
    ed += 2.0f*d;   // pair appears twice in directed list
  }
  float ca[Q], da[Q]; float ea = 0.0f;
  #pragma unroll
  for (int q=0;q<Q;q++){ ca[q]=0.0f; da[q]=0.0f; }
  for (int n = blockIdx.x*256 + t; n < N; n += gS*256){
    const float4* a = (const float4*)(psi + (size_t)n*Q);
    float pv[Q];
    #pragma unroll
    for (int i=0;i<4;i++){ float4 x=a[i]; pv[4*i]=x.x; pv[4*i+1]=x.y; pv[4*i+2]=x.z; pv[4*i+3]=x.w; }
    const float dg = (float)deg[n];
    #pragma unroll
    for (int q=0;q<Q;q++){
      ca[q] += pv[q];
      da[q] += pv[q]*dg;
      ea    -= pv[q]*__logf(pv[q]+1e-12f);
    }
  }
  __shared__ float smc[4][17], smd[4][17];
  __shared__ float sme[4], smeE[4];
  __shared__ float smg[16][17], smg2[16][17];
  __shared__ int amL;
  #pragma unroll
  for (int q=0;q<Q;q++){
    float s  = wsum(ca[q]);
    float s2 = wsum(da[q]);
    if (lane == 0){ smc[wid][q]=s; smd[wid][q]=s2; }
  }
  float se = wsum(ea);
  float sed = wsum(ed);
  if (lane == 0){ sme[wid]=se; smeE[wid]=sed; }
  __syncthreads();
  if (t < Q){
    colpart[(size_t)blockIdx.x*Q+t] = smc[0][t]+smc[1][t]+smc[2][t]+smc[3][t];
    degpart[(size_t)blockIdx.x*Q+t] = smd[0][t]+smd[1][t]+smd[2][t]+smd[3][t];
  }
  if (t == 0){
    entpart[blockIdx.x]  = sme[0]+sme[1]+sme[2]+sme[3];
    edgepart[blockIdx.x] = smeE[0]+smeE[1]+smeE[2]+smeE[3];
  }
  __threadfence();
  if (t == 0) amL = (atomicAdd(cnt, 1) == gS-1);
  __syncthreads();
  if (!amL) return;
  {
    const int g = t>>4, qq = t&15;
    float cs=0.0f, ds=0.0f;
    for (int r = g; r < gS; r += 16){
      cs += colpart[(size_t)r*Q + qq];
      ds += degpart[(size_t)r*Q + qq];
    }
    smg[g][qq] = cs; smg2[g][qq] = ds;
    __syncthreads();
    float colq=0.0f, degq=0.0f;
    if (t < Q){
      #pragma unroll
      for (int i=0;i<16;i++){ colq += smg[i][t]; degq += smg2[i][t]; }
    }
    float es=0.0f, en=0.0f;
    for (int i=t; i<gS; i+=256){ es += edgepart[i]; en += entpart[i]; }
    es = wsum(es); en = wsum(en);
    if (lane == 0){ smeE[wid]=es; sme[wid]=en; }
    __syncthreads();
    if (t < Q){ smg[0][t] = colq; smg2[0][t] = degq; }
    __syncthreads();
    if (t == 0){
      const float edge_total = smeE[0]+smeE[1]+smeE[2]+smeE[3];
      const float ent_total  = sme[0]+sme[1]+sme[2]+sme[3];
      float reg = 0.0f, dt = 0.0f;
      for (int i=0;i<Q;i++){
        float d = smg[0][i]/(float)N - 1.0f/(float)Q; reg += d*d;
        float s = smg2[0][i]/m2; dt += s*s;
      }
      out[NQ+0] = reg * 4.0f;                                // * sqrt(16)
      out[NQ+1] = ent_total/(float)N / 2.7725887222397811f;  // / log(16)
      out[NQ+2] = edge_total/m2 - dt;
    }
  }
}

extern "C" void kernel_launch(void* const* d_in, const int* in_sizes, int n_in,
                              void* d_out, int out_size, void* d_ws, size_t ws_size,
                              hipStream_t stream)
{
  const int*   src   = (const int*)  d_in[0];
  const int*   dst   = (const int*)  d_in[1];
  // d_in[2] = rev : structurally rev[p]=p+M / p-M, exploited directly
  const float* psi0  = (const float*)d_in[3];
  const float* msg0  = (const float*)d_in[4];
  const float* betap = (const float*)d_in[5];

  const int E  = in_sizes[0];
  const int M  = E/2;
  const int NQ = in_sizes[3];
  const int N  = NQ/Q;
  const float mean_w = (float)((double)E/((double)N*(double)N));
  const float m2 = (float)E;

  const int B = 256;
  const int gE = (E+B-1)/B, gN = (N+B-1)/B;
  const int nb = (N+SCAN_B-1)/SCAN_B;
  const int nbE = 2048;                          // edge grid (grid-stride)
  const int gW = (N+3)/4;                        // gather: one wave per node
  const int nchG = (gW+63)>>6;                   // gather h-chunks (~196)
  const int gS = 256;                            // stats grid

  char* w = (char*)d_ws;
  float* msgC    = (float*)w; w += (size_t)E*Q*sizeof(float);
  float* nl      = (float*)w; w += (size_t)NQ*sizeof(float);
  int*   ipos    = (int*)  w; w += (size_t)E*sizeof(int);
  int*   offs    = (int*)  w; w += (size_t)(N+16)*sizeof(int);
  int*   cursor  = (int*)  w; w += (size_t)(N+16)*sizeof(int);
  int*   bsum    = (int*)  w; w += 256*sizeof(int);
  float* hp0     = (float*)w; w += (size_t)gN*Q*sizeof(float);
  float* edgepart= (float*)w; w += (size_t)gS*sizeof(float);
  float* colpart = (float*)w; w += (size_t)gS*Q*sizeof(float);
  float* degpart = (float*)w; w += (size_t)gS*Q*sizeof(float);
  float* entpart = (float*)w; w += (size_t)gS*sizeof(float);
  int*   deg     = (int*)  w; w += (size_t)(N+16)*sizeof(int);   // memset from here
  float* hpart2  = (float*)w; w += (size_t)10*nchG*Q*sizeof(float);
  float* diffpart= (float*)w; w += (size_t)10*nbE*sizeof(float);
  float* harr    = (float*)w; w += (size_t)10*Q*sizeof(float);
  int*   donep   = (int*)  w; w += 4*sizeof(int);
  int*   cnts    = (int*)  w; w += 4*sizeof(int);

  float* psi = (float*)d_out;   // [N,Q]; scalars at NQ..NQ+2

  const size_t small_bytes = (size_t)((char*)w - (char*)deg);
  hipMemsetAsync(deg, 0, small_bytes, stream);   // deg, hpart2, diff, h, flags

  // one-time: psi0 partials, CSR build (ipos) + scatter msg0->msgC, nl_0
  k_h_part  <<<gN,B,0,stream>>>(psi0, hp0, N);
  k_deg     <<<gE,B,0,stream>>>(dst, deg, E);
  k_scan1   <<<nb,SCAN_B,0,stream>>>(deg, offs, bsum, N);
  k_scan2   <<<1, SCAN_B,0,stream>>>(bsum, nb);
  k_scan3   <<<nb,SCAN_B,0,stream>>>(offs, cursor, bsum, N, E);
  k_fillCS  <<<gE,B,0,stream>>>(dst, cursor, msg0, msgC, ipos, E);
  k_gatherF2<<<gW,B,0,stream>>>(msgC, offs, nl, harr, psi, betap, donep,
                                hpart2, N, 0);

  for (int k=0; k<10; ++k) {
    const float* hs  = (k==0) ? hp0 : (hpart2 + (size_t)(k-1)*nchG*Q);
    const int    nch = (k==0) ? gN : nchG;
    const float* dp  = diffpart + (size_t)(k>0 ? k-1 : 0)*nbE;
    k_edgeF   <<<nbE,B,0,stream>>>(src, dst, ipos, msgC, nl, betap,
                                   hs, nch, dp, nbE,
                                   diffpart + (size_t)k*nbE, harr + (size_t)k*Q,
                                   donep, M, mean_w, k);
    k_gatherF2<<<gW,B,0,stream>>>(msgC, offs, nl, harr + (size_t)k*Q, psi,
                                  betap, donep,
                                  hpart2 + (size_t)k*nchG*Q, N, 1);
  }

  k_stats<<<gS,B,0,stream>>>(src, dst, psi, deg, colpart, degpart,
                             entpart, edgepart, cnts, psi, M, N, NQ, m2, gS);
}